// Round 11
// baseline (353.234 us; speedup 1.0000x reference)
//
#include <hip/hip_runtime.h>
#include <hip/hip_bf16.h>
#include <stdint.h>

#define HN 128      // hidden size
#define TSTEPS 250
#define ON 20       // output size
#define GK 700      // input size
#define NKT 22      // GEMM k-tiles of 32 (700 = 21*32 + 28)

typedef _Float16 h2 __attribute__((ext_vector_type(2)));

__device__ __forceinline__ h2 bch_u(uint32_t u) { return __builtin_bit_cast(h2, u); }
__device__ __forceinline__ h2 bch_f(float f)    { return __builtin_bit_cast(h2, f); }
__device__ __forceinline__ float fdot2(h2 a, h2 b, float c) {
    return __builtin_amdgcn_fdot2(a, b, c, false);
}
__device__ __forceinline__ float pack2(float x, float y) {
    h2 p; p.x = (_Float16)x; p.y = (_Float16)y;
    return __builtin_bit_cast(float, p);
}
__device__ __forceinline__ uint32_t pack2u(float x, float y) {
    h2 p; p.x = (_Float16)x; p.y = (_Float16)y;
    return __builtin_bit_cast(uint32_t, p);
}

// ---------------------------------------------------------------------------
// Phase A: in1_ff[bt,h] = X[bt,:] . W_ih1[h,:] + b_ih1[h]
// M=64000, N=128, K=700. f16 k-pair LDS staging + v_dot2_f32_f16 (2 MACs/
// inst, fp32 accum). A-reads wave-broadcast; B-reads 2-way via +16B swizzle.
// Double-buffered LDS, reg prefetch, 1 barrier/tile.
// ---------------------------------------------------------------------------
__global__ __launch_bounds__(256) void ff_gemm(const float* __restrict__ X,
                                               const float* __restrict__ W,
                                               const float* __restrict__ bias,
                                               float* __restrict__ out) {
    __shared__ uint32_t Xh[2][16][128];   // [buf][k-pair][row]       8 KB x2
    __shared__ uint32_t Wh[2][16][132];   // [buf][k-pair][col swz]  8.4 KB x2
    const int tid  = threadIdx.x;
    const int tx   = tid & 15;
    const int ty   = tid >> 4;
    const int m0   = blockIdx.x * 128;
    const int r    = tid >> 1;      // staged row (X) / col (W), 0..127
    const int half = tid & 1;       // k-halves 0..15 / 16..31
    const int rsw  = r + ((r >> 5) & 1) * 4;            // W store swizzle
    const int bsw  = tx * 8 + ((tx >> 2) & 1) * 4;      // W read swizzle

    float acc[8][8];
#pragma unroll
    for (int i = 0; i < 8; ++i)
#pragma unroll
        for (int n = 0; n < 8; ++n) acc[i][n] = 0.f;

    float xv[16], wv[16];

#define LOADT(t)                                                               \
    {                                                                          \
        const int kb = (t) * 32 + half * 16;                                   \
        if ((t) < 21) {                                                        \
            _Pragma("unroll")                                                  \
            for (int q = 0; q < 4; ++q) {                                      \
                *(float4*)&xv[q * 4] =                                         \
                    *(const float4*)&X[(size_t)(m0 + r) * GK + kb + q * 4];    \
                *(float4*)&wv[q * 4] =                                         \
                    *(const float4*)&W[(size_t)r * GK + kb + q * 4];           \
            }                                                                  \
        } else {                                                               \
            _Pragma("unroll")                                                  \
            for (int c = 0; c < 16; ++c) {                                     \
                const int k = kb + c;                                          \
                xv[c] = (k < GK) ? X[(size_t)(m0 + r) * GK + k] : 0.f;         \
                wv[c] = (k < GK) ? W[(size_t)r * GK + k] : 0.f;                \
            }                                                                  \
        }                                                                      \
    }
#define STORET(buf)                                                            \
    {                                                                          \
        _Pragma("unroll")                                                      \
        for (int e = 0; e < 8; ++e) {                                          \
            Xh[buf][half * 8 + e][r]   = pack2u(xv[2 * e], xv[2 * e + 1]);     \
            Wh[buf][half * 8 + e][rsw] = pack2u(wv[2 * e], wv[2 * e + 1]);     \
        }                                                                      \
    }

    LOADT(0);
    STORET(0);
    __syncthreads();
    int cur = 0;
    for (int t = 0; t < NKT; ++t) {
        if (t + 1 < NKT) LOADT(t + 1);          // issue early; hides under compute
#pragma unroll
        for (int p = 0; p < 16; ++p) {
            uint4 a0 = *(const uint4*)&Xh[cur][p][ty * 8];
            uint4 a1 = *(const uint4*)&Xh[cur][p][ty * 8 + 4];
            uint4 b0 = *(const uint4*)&Wh[cur][p][bsw];
            uint4 b1 = *(const uint4*)&Wh[cur][p][bsw + 4];
            const h2 av[8] = {bch_u(a0.x), bch_u(a0.y), bch_u(a0.z), bch_u(a0.w),
                              bch_u(a1.x), bch_u(a1.y), bch_u(a1.z), bch_u(a1.w)};
            const h2 bv[8] = {bch_u(b0.x), bch_u(b0.y), bch_u(b0.z), bch_u(b0.w),
                              bch_u(b1.x), bch_u(b1.y), bch_u(b1.z), bch_u(b1.w)};
#pragma unroll
            for (int i = 0; i < 8; ++i)
#pragma unroll
                for (int n = 0; n < 8; ++n)
                    acc[i][n] = fdot2(av[i], bv[n], acc[i][n]);
        }
        if (t + 1 < NKT) STORET(cur ^ 1);       // disjoint buffer from readers
        __syncthreads();
        cur ^= 1;
    }

    const float4 bv0 = *(const float4*)&bias[tx * 8];
    const float4 bv1 = *(const float4*)&bias[tx * 8 + 4];
#pragma unroll
    for (int i = 0; i < 8; ++i) {
        const size_t row = (size_t)(m0 + ty * 8 + i);
        float4 v0, v1;
        v0.x = acc[i][0] + bv0.x; v0.y = acc[i][1] + bv0.y;
        v0.z = acc[i][2] + bv0.z; v0.w = acc[i][3] + bv0.w;
        v1.x = acc[i][4] + bv1.x; v1.y = acc[i][5] + bv1.y;
        v1.z = acc[i][6] + bv1.z; v1.w = acc[i][7] + bv1.w;
        *(float4*)&out[row * HN + tx * 8]     = v0;
        *(float4*)&out[row * HN + tx * 8 + 4] = v1;
    }
#undef LOADT
#undef STORET
}

// ---------------------------------------------------------------------------
// single-row 128-dot against wave-uniform spike vector sv[16] (128 f16).
// Row j's weights k-major packed: WP[t][j] = w[j][8t..8t+7].
// ---------------------------------------------------------------------------
__device__ __forceinline__ float mv1h(const float4 (&WP)[16][HN],
                                      const uint4 (&sv)[16], int j) {
    float a0 = 0.f, a1 = 0.f, a2 = 0.f, a3 = 0.f;
#pragma unroll
    for (int t = 0; t < 16; ++t) {
        const float4 wl = WP[t][j];
        const uint4  s  = sv[t];
        a0 = fdot2(bch_f(wl.x), bch_u(s.x), a0);
        a1 = fdot2(bch_f(wl.y), bch_u(s.y), a1);
        a2 = fdot2(bch_f(wl.z), bch_u(s.z), a2);
        a3 = fdot2(bch_f(wl.w), bch_u(s.w), a3);
    }
    return (a0 + a1) + (a2 + a3);
}
__device__ __forceinline__ float mv1o(const float4 (&WP)[16][32],
                                      const uint4 (&sv)[16], int j) {
    float a0 = 0.f, a1 = 0.f, a2 = 0.f, a3 = 0.f;
#pragma unroll
    for (int t = 0; t < 16; ++t) {
        const float4 wl = WP[t][j];
        const uint4  s  = sv[t];
        a0 = fdot2(bch_f(wl.x), bch_u(s.x), a0);
        a1 = fdot2(bch_f(wl.y), bch_u(s.y), a1);
        a2 = fdot2(bch_f(wl.z), bch_u(s.z), a2);
        a3 = fdot2(bch_f(wl.w), bch_u(s.w), a3);
    }
    return (a0 + a1) + (a2 + a3);
}

#define LOADSPIKES(arr, buf, sv)                                               \
    {                                                                          \
        const uint4* _p = (const uint4*)&arr[buf][0];                          \
        _Pragma("unroll") for (int _t = 0; _t < 16; ++_t) sv[_t] = _p[_t];     \
    }

// ---------------------------------------------------------------------------
// Phase B: f16-LDS dot2 pipeline, 6 heavy waves (all 8 waves working).
// Roles (slot i, one barrier each):
//   w0,w1: S1 -> s1(i)   w2,w3: B -> pB(i-1)   w4,w5: C+L2 -> s2(i-2)
//   w6: RO -> rdot(i-3)  w7: OM -> om/softmax(i-4)
// ---------------------------------------------------------------------------
__global__ __launch_bounds__(512) void srnn_pipe8(
    const float* __restrict__ ff,
    const float* __restrict__ W_h1h1, const float* __restrict__ b_h1h1,
    const float* __restrict__ W_h1h2, const float* __restrict__ b_h1h2,
    const float* __restrict__ W_h2h2, const float* __restrict__ b_h2h2,
    const float* __restrict__ W_h2o,  const float* __restrict__ b_h2o,
    const float* __restrict__ tau_adp_h1, const float* __restrict__ tau_adp_h2,
    const float* __restrict__ tau_m_h1,   const float* __restrict__ tau_m_h2,
    const float* __restrict__ tau_m_o,
    const float* __restrict__ h1m0, const float* __restrict__ h2m0,
    const float* __restrict__ om0,
    float* __restrict__ out) {
    const int b    = blockIdx.x;
    const int tid  = threadIdx.x;
    const int w    = tid >> 6;
    const int lane = tid & 63;

    __shared__ float4 WPA[16][HN];   // 32 KB  W_h1h1 f16 k-major
    __shared__ float4 WPB[16][HN];   // 32 KB  W_h1h2
    __shared__ float4 WPC[16][HN];   // 32 KB  W_h2h2
    __shared__ float4 WPO[16][32];   //  8 KB  W_h2o (rows 0..19, rest zero)
    __shared__ _Float16 s1h[2][HN];
    __shared__ _Float16 s2h[2][HN];
    __shared__ float pBbuf[2][HN];
    __shared__ float rdot_lds[2][32];

    // ---- stage weights fp32->f16 (one time) ----
#pragma unroll
    for (int e = tid; e < 2048; e += 512) {
        const int t = e >> 7, j = e & 127;
        {
            const float* s = W_h1h1 + j * HN + t * 8;
            float4 x0 = *(const float4*)s, x1 = *(const float4*)(s + 4);
            float4 d; d.x = pack2(x0.x, x0.y); d.y = pack2(x0.z, x0.w);
            d.z = pack2(x1.x, x1.y); d.w = pack2(x1.z, x1.w);
            WPA[t][j] = d;
        }
        {
            const float* s = W_h1h2 + j * HN + t * 8;
            float4 x0 = *(const float4*)s, x1 = *(const float4*)(s + 4);
            float4 d; d.x = pack2(x0.x, x0.y); d.y = pack2(x0.z, x0.w);
            d.z = pack2(x1.x, x1.y); d.w = pack2(x1.z, x1.w);
            WPB[t][j] = d;
        }
        {
            const float* s = W_h2h2 + j * HN + t * 8;
            float4 x0 = *(const float4*)s, x1 = *(const float4*)(s + 4);
            float4 d; d.x = pack2(x0.x, x0.y); d.y = pack2(x0.z, x0.w);
            d.z = pack2(x1.x, x1.y); d.w = pack2(x1.z, x1.w);
            WPC[t][j] = d;
        }
    }
    {
        const int t = tid >> 5, j = tid & 31;   // 512 = 16*32 exactly
        float4 d = {0.f, 0.f, 0.f, 0.f};
        if (j < ON) {
            const float* s = W_h2o + j * HN + t * 8;
            float4 x0 = *(const float4*)s, x1 = *(const float4*)(s + 4);
            d.x = pack2(x0.x, x0.y); d.y = pack2(x0.z, x0.w);
            d.z = pack2(x1.x, x1.y); d.w = pack2(x1.z, x1.w);
        }
        WPO[t][j] = d;
    }
    if (tid < HN) {
        s1h[0][tid] = (_Float16)0; s1h[1][tid] = (_Float16)0;
        s2h[0][tid] = (_Float16)0; s2h[1][tid] = (_Float16)0;
    }
    __syncthreads();

    if (w < 2) {
        // ================= S1: layer-1 LIF, j = w*64+lane =================
        const int j = (w << 6) + lane;
        float h1m = h1m0[b * HN + j];
        const float a1 = expf(-1.f / tau_m_h1[j]);
        const float r1 = expf(-1.f / tau_adp_h1[j]);
        const float bi = b_h1h1[j];
        float b1 = 0.01f, s1p = 0.f;
        const float* fp = ff + (size_t)b * TSTEPS * HN + j;
        float fc = fp[0], fn = fp[HN];
        for (int i = 0; i < TSTEPS + 4; ++i) {
            if (i < TSTEPS) {
                const float f2 = (i + 2 < TSTEPS) ? fp[(size_t)(i + 2) * HN] : 0.f;
                uint4 sv[16];
                LOADSPIKES(s1h, (i + 1) & 1, sv);          // s1(i-1)
                const float pA = mv1h(WPA, sv, j);
                b1 = r1 * b1 + (1.f - r1) * s1p;
                const float Bt = 0.01f + 1.8f * b1;
                h1m = h1m * a1 + (1.f - a1) * (fc + bi + pA) - Bt * s1p;
                s1p = (h1m - Bt > 0.f) ? 1.f : 0.f;
                s1h[i & 1][j] = (_Float16)s1p;
                fc = fn; fn = f2;
            }
            __syncthreads();
        }
    } else if (w < 4) {
        // ================= B: pB(i-1) = W_h1h2 . s1(i-1) =================
        const int j = ((w - 2) << 6) + lane;
        for (int i = 0; i < TSTEPS + 4; ++i) {
            if (i >= 1 && i <= TSTEPS) {
                uint4 sv[16];
                LOADSPIKES(s1h, (i - 1) & 1, sv);
                pBbuf[(i - 1) & 1][j] = mv1h(WPB, sv, j);
            }
            __syncthreads();
        }
    } else if (w < 6) {
        // ================= C + LIF2: s2(i-2), j = (w-4)*64+lane ============
        const int j = ((w - 4) << 6) + lane;
        float h2m = h2m0[b * HN + j];
        const float a2 = expf(-1.f / tau_m_h2[j]);
        const float r2 = expf(-1.f / tau_adp_h2[j]);
        const float bi = b_h1h2[j] + b_h2h2[j];
        float b2v = 0.01f, s2p = 0.f;
        for (int i = 0; i < TSTEPS + 4; ++i) {
            if (i >= 2 && i <= TSTEPS + 1) {
                const int k2 = i - 2;
                uint4 sv[16];
                LOADSPIKES(s2h, (k2 + 1) & 1, sv);         // s2(k2-1)
                const float pC = mv1h(WPC, sv, j);
                const float in2 = pBbuf[k2 & 1][j] + pC + bi;
                b2v = r2 * b2v + (1.f - r2) * s2p;
                const float Bt = 0.01f + 1.8f * b2v;
                h2m = h2m * a2 + (1.f - a2) * in2 - Bt * s2p;
                s2p = (h2m - Bt > 0.f) ? 1.f : 0.f;
                s2h[k2 & 1][j] = (_Float16)s2p;
            }
            __syncthreads();
        }
    } else if (w == 6) {
        // ================= RO: rdot(i-3) = W_h2o . s2(i-3) =================
        const int o = lane;
        for (int i = 0; i < TSTEPS + 4; ++i) {
            if (i >= 3 && i <= TSTEPS + 2 && o < ON) {
                const int k3 = i - 3;
                uint4 sv[16];
                LOADSPIKES(s2h, k3 & 1, sv);
                rdot_lds[k3 & 1][o] = mv1o(WPO, sv, o);
            }
            __syncthreads();
        }
    } else {
        // ================= OM: leaky readout + softmax accumulate ==========
        const int o = lane;
        float om = 0.f, ao = 0.f, bo = 0.f, acc = 0.f;
        if (o < ON) {
            om = om0[b * ON + o];
            ao = expf(-1.f / tau_m_o[o]);
            bo = b_h2o[o];
        }
        for (int i = 0; i < TSTEPS + 4; ++i) {
            if (i >= 4) {
                const int k4 = i - 4;
                if (o < ON)
                    om = om * ao + (1.f - ao) * (rdot_lds[k4 & 1][o] + bo);
                float mx = (o < ON) ? om : -3.4e38f;
#pragma unroll
                for (int m = 16; m >= 1; m >>= 1)
                    mx = fmaxf(mx, __shfl_xor(mx, m));
                float e = (o < ON) ? __expf(om - mx) : 0.f;
                float den = e;
#pragma unroll
                for (int m = 16; m >= 1; m >>= 1)
                    den += __shfl_xor(den, m);
                if (o < ON && k4 > 10) acc += e / den;
            }
            __syncthreads();
        }
        if (o < ON) out[b * ON + o] = acc;
    }
}

// ---------------------------------------------------------------------------
// Phase C: A_norm = sum|W_h1h1| + sum|W_h2h2|  -> out[5120]  (exact fp32)
// ---------------------------------------------------------------------------
__global__ void anorm_kernel(const float* __restrict__ W1,
                             const float* __restrict__ W2,
                             float* __restrict__ out) {
    __shared__ float red[256];
    float s = 0.f;
    for (int i = threadIdx.x; i < HN * HN; i += 256)
        s += fabsf(W1[i]) + fabsf(W2[i]);
    red[threadIdx.x] = s;
    __syncthreads();
    for (int off = 128; off > 0; off >>= 1) {
        if (threadIdx.x < off) red[threadIdx.x] += red[threadIdx.x + off];
        __syncthreads();
    }
    if (threadIdx.x == 0) out[256 * ON] = red[0];
}

extern "C" void kernel_launch(void* const* d_in, const int* in_sizes, int n_in,
                              void* d_out, int out_size, void* d_ws, size_t ws_size,
                              hipStream_t stream) {
    const float* input      = (const float*)d_in[0];
    // d_in[1], d_in[2]: A1_mask/A2_mask -- all-ones, unused by reference math
    const float* W_ih1      = (const float*)d_in[3];
    const float* b_ih1      = (const float*)d_in[4];
    const float* W_h1h1     = (const float*)d_in[5];
    const float* b_h1h1     = (const float*)d_in[6];
    const float* W_h1h2     = (const float*)d_in[7];
    const float* b_h1h2     = (const float*)d_in[8];
    const float* W_h2h2     = (const float*)d_in[9];
    const float* b_h2h2     = (const float*)d_in[10];
    const float* W_h2o      = (const float*)d_in[11];
    const float* b_h2o      = (const float*)d_in[12];
    const float* tau_adp_h1 = (const float*)d_in[13];
    const float* tau_adp_h2 = (const float*)d_in[14];
    const float* tau_m_h1   = (const float*)d_in[15];
    const float* tau_m_h2   = (const float*)d_in[16];
    const float* tau_m_o    = (const float*)d_in[17];
    const float* h1m0       = (const float*)d_in[18];
    const float* h2m0       = (const float*)d_in[19];
    const float* om0        = (const float*)d_in[20];

    float* out   = (float*)d_out;
    float* ffbuf = (float*)d_ws;   // 256*250*128*4 = 32.768 MB

    anorm_kernel<<<1, 256, 0, stream>>>(W_h1h1, W_h2h2, out);
    ff_gemm<<<500, 256, 0, stream>>>(input, W_ih1, b_ih1, ffbuf);
    srnn_pipe8<<<256, 512, 0, stream>>>(ffbuf, W_h1h1, b_h1h1, W_h1h2, b_h1h2,
                                        W_h2h2, b_h2h2, W_h2o, b_h2o,
                                        tau_adp_h1, tau_adp_h2,
                                        tau_m_h1, tau_m_h2, tau_m_o,
                                        h1m0, h2m0, om0, out);
}

// Round 12
// 262.047 us; speedup vs baseline: 1.3480x; 1.3480x over previous
//
#include <hip/hip_runtime.h>
#include <hip/hip_bf16.h>
#include <stdint.h>

#define HN 128      // hidden size
#define TSTEPS 250
#define ON 20       // output size
#define GK 700      // input size
#define NKT 22      // GEMM k-tiles of 32 (700 = 21*32 + 28, zero-padded)

typedef _Float16 h2 __attribute__((ext_vector_type(2)));
typedef _Float16 h8 __attribute__((ext_vector_type(8)));
typedef float f4 __attribute__((ext_vector_type(4)));

__device__ __forceinline__ h2 bch_u(uint32_t u) { return __builtin_bit_cast(h2, u); }
__device__ __forceinline__ h2 bch_f(float f)    { return __builtin_bit_cast(h2, f); }
__device__ __forceinline__ float fdot2(h2 a, h2 b, float c) {
    return __builtin_amdgcn_fdot2(a, b, c, false);
}
__device__ __forceinline__ float pack2(float x, float y) {
    h2 p; p.x = (_Float16)x; p.y = (_Float16)y;
    return __builtin_bit_cast(float, p);
}
__device__ __forceinline__ uint32_t pack2u(float x, float y) {
    h2 p; p.x = (_Float16)x; p.y = (_Float16)y;
    return __builtin_bit_cast(uint32_t, p);
}

// ---------------------------------------------------------------------------
// Phase A: in1_ff[bt,h] = X[bt,:] . W_ih1[h,:] + b_ih1[h]
// M=64000, N=128, K=700(pad 704). f16 MFMA 16x16x32: 128x128 tile, 4 waves,
// each wave 2(M) x 8(N) fragments. LDS tiles [128][32] f16 row-major (64B
// rows) -> all fragment ds_read_b128 are exact 1KB/wave covers, conflict-
// free. Double-buffered, global->reg issue-early staging.
// Fragment maps (m89-verified): A lane: row=l&15, k=(l>>4)*8+j;
// B lane: col=l&15, k=(l>>4)*8+j; D lane: col=l&15, row=(l>>4)*4+q.
// ---------------------------------------------------------------------------
__global__ __launch_bounds__(256) void ff_gemm(const float* __restrict__ X,
                                               const float* __restrict__ W,
                                               const float* __restrict__ bias,
                                               float* __restrict__ out) {
    __shared__ __align__(16) uint32_t Xs[2][128][16];   // 8 KB x2 (f16 pairs)
    __shared__ __align__(16) uint32_t Ws[2][128][16];   // 8 KB x2
    const int tid   = threadIdx.x;
    const int w     = tid >> 6;
    const int lane  = tid & 63;
    const int m0    = blockIdx.x * 128;
    const int srow  = tid & 127;   // staged row (X) / col-row (W)
    const int shalf = tid >> 7;    // k-pair half: 0 -> pairs 0..7, 1 -> 8..15
    const int lr    = lane & 15;
    const int lg    = lane >> 4;

    f4 acc[2][8];
#pragma unroll
    for (int m = 0; m < 2; ++m)
#pragma unroll
        for (int n = 0; n < 8; ++n) acc[m][n] = (f4){0.f, 0.f, 0.f, 0.f};

    float4 x4[4], w4[4];

#define LOADT(t)                                                               \
    {                                                                          \
        const int k0 = (t) * 32 + shalf * 16;                                  \
        if ((t) < 21 || shalf == 0) {                                          \
            _Pragma("unroll")                                                  \
            for (int q = 0; q < 4; ++q) {                                      \
                x4[q] = *(const float4*)&X[(size_t)(m0 + srow) * GK + k0 + q * 4]; \
                w4[q] = *(const float4*)&W[(size_t)srow * GK + k0 + q * 4];    \
            }                                                                  \
        } else {  /* t==21, shalf==1: k0=688, valid 688..699 = 3 float4 */     \
            _Pragma("unroll")                                                  \
            for (int q = 0; q < 3; ++q) {                                      \
                x4[q] = *(const float4*)&X[(size_t)(m0 + srow) * GK + k0 + q * 4]; \
                w4[q] = *(const float4*)&W[(size_t)srow * GK + k0 + q * 4];    \
            }                                                                  \
            x4[3] = (float4){0.f, 0.f, 0.f, 0.f};                              \
            w4[3] = (float4){0.f, 0.f, 0.f, 0.f};                              \
        }                                                                      \
    }
#define STORET(buf)                                                            \
    {                                                                          \
        _Pragma("unroll")                                                      \
        for (int q = 0; q < 4; ++q) {                                          \
            Xs[buf][srow][shalf * 8 + 2 * q]     = pack2u(x4[q].x, x4[q].y);   \
            Xs[buf][srow][shalf * 8 + 2 * q + 1] = pack2u(x4[q].z, x4[q].w);   \
            Ws[buf][srow][shalf * 8 + 2 * q]     = pack2u(w4[q].x, w4[q].y);   \
            Ws[buf][srow][shalf * 8 + 2 * q + 1] = pack2u(w4[q].z, w4[q].w);   \
        }                                                                      \
    }

    LOADT(0);
    STORET(0);
    __syncthreads();
    int cur = 0;
    for (int t = 0; t < NKT; ++t) {
        if (t + 1 < NKT) LOADT(t + 1);   // issue early; hides under MFMA
        h8 a[2];
#pragma unroll
        for (int m = 0; m < 2; ++m) {
            const uint4 au = *(const uint4*)&Xs[cur][w * 32 + m * 16 + lr][lg * 4];
            a[m] = __builtin_bit_cast(h8, au);
        }
#pragma unroll
        for (int n = 0; n < 8; ++n) {
            const uint4 bu = *(const uint4*)&Ws[cur][n * 16 + lr][lg * 4];
            const h8 bf = __builtin_bit_cast(h8, bu);
            acc[0][n] = __builtin_amdgcn_mfma_f32_16x16x32_f16(a[0], bf, acc[0][n], 0, 0, 0);
            acc[1][n] = __builtin_amdgcn_mfma_f32_16x16x32_f16(a[1], bf, acc[1][n], 0, 0, 0);
        }
        if (t + 1 < NKT) STORET(cur ^ 1);   // disjoint buffer from readers
        __syncthreads();
        cur ^= 1;
    }

    float bv[8];
#pragma unroll
    for (int n = 0; n < 8; ++n) bv[n] = bias[n * 16 + lr];
#pragma unroll
    for (int m = 0; m < 2; ++m)
#pragma unroll
        for (int q = 0; q < 4; ++q) {
            const size_t row = (size_t)(m0 + w * 32 + m * 16 + lg * 4 + q);
#pragma unroll
            for (int n = 0; n < 8; ++n)
                out[row * HN + n * 16 + lr] = acc[m][n][q] + bv[n];
        }
#undef LOADT
#undef STORET
}

// ---------------------------------------------------------------------------
// single-row 128-dot against wave-uniform spike vector sv[16] (128 f16).
// Row j's weights k-major packed: WP[t][j] = w[j][8t..8t+7].
// ---------------------------------------------------------------------------
__device__ __forceinline__ float mv1h(const float4 (&WP)[16][HN],
                                      const uint4 (&sv)[16], int j) {
    float a0 = 0.f, a1 = 0.f, a2 = 0.f, a3 = 0.f;
#pragma unroll
    for (int t = 0; t < 16; ++t) {
        const float4 wl = WP[t][j];
        const uint4  s  = sv[t];
        a0 = fdot2(bch_f(wl.x), bch_u(s.x), a0);
        a1 = fdot2(bch_f(wl.y), bch_u(s.y), a1);
        a2 = fdot2(bch_f(wl.z), bch_u(s.z), a2);
        a3 = fdot2(bch_f(wl.w), bch_u(s.w), a3);
    }
    return (a0 + a1) + (a2 + a3);
}
__device__ __forceinline__ float mv1o(const float4 (&WP)[16][32],
                                      const uint4 (&sv)[16], int j) {
    float a0 = 0.f, a1 = 0.f, a2 = 0.f, a3 = 0.f;
#pragma unroll
    for (int t = 0; t < 16; ++t) {
        const float4 wl = WP[t][j];
        const uint4  s  = sv[t];
        a0 = fdot2(bch_f(wl.x), bch_u(s.x), a0);
        a1 = fdot2(bch_f(wl.y), bch_u(s.y), a1);
        a2 = fdot2(bch_f(wl.z), bch_u(s.z), a2);
        a3 = fdot2(bch_f(wl.w), bch_u(s.w), a3);
    }
    return (a0 + a1) + (a2 + a3);
}

#define LOADSPIKES(arr, buf, sv)                                               \
    {                                                                          \
        const uint4* _p = (const uint4*)&arr[buf][0];                          \
        _Pragma("unroll") for (int _t = 0; _t < 16; ++_t) sv[_t] = _p[_t];     \
    }

// ---------------------------------------------------------------------------
// Phase B: f16-LDS dot2 pipeline, 6 heavy waves (all 8 waves working).
// Roles (slot i, one barrier each):
//   w0,w1: S1 -> s1(i)   w2,w3: B -> pB(i-1)   w4,w5: C+L2 -> s2(i-2)
//   w6: RO -> rdot(i-3)  w7: OM -> om/softmax(i-4)
// ---------------------------------------------------------------------------
__global__ __launch_bounds__(512) void srnn_pipe8(
    const float* __restrict__ ff,
    const float* __restrict__ W_h1h1, const float* __restrict__ b_h1h1,
    const float* __restrict__ W_h1h2, const float* __restrict__ b_h1h2,
    const float* __restrict__ W_h2h2, const float* __restrict__ b_h2h2,
    const float* __restrict__ W_h2o,  const float* __restrict__ b_h2o,
    const float* __restrict__ tau_adp_h1, const float* __restrict__ tau_adp_h2,
    const float* __restrict__ tau_m_h1,   const float* __restrict__ tau_m_h2,
    const float* __restrict__ tau_m_o,
    const float* __restrict__ h1m0, const float* __restrict__ h2m0,
    const float* __restrict__ om0,
    float* __restrict__ out) {
    const int b    = blockIdx.x;
    const int tid  = threadIdx.x;
    const int w    = tid >> 6;
    const int lane = tid & 63;

    __shared__ float4 WPA[16][HN];   // 32 KB  W_h1h1 f16 k-major
    __shared__ float4 WPB[16][HN];   // 32 KB  W_h1h2
    __shared__ float4 WPC[16][HN];   // 32 KB  W_h2h2
    __shared__ float4 WPO[16][32];   //  8 KB  W_h2o (rows 0..19, rest zero)
    __shared__ _Float16 s1h[2][HN];
    __shared__ _Float16 s2h[2][HN];
    __shared__ float pBbuf[2][HN];
    __shared__ float rdot_lds[2][32];

    // ---- stage weights fp32->f16 (one time) ----
#pragma unroll
    for (int e = tid; e < 2048; e += 512) {
        const int t = e >> 7, j = e & 127;
        {
            const float* s = W_h1h1 + j * HN + t * 8;
            float4 x0 = *(const float4*)s, x1 = *(const float4*)(s + 4);
            float4 d; d.x = pack2(x0.x, x0.y); d.y = pack2(x0.z, x0.w);
            d.z = pack2(x1.x, x1.y); d.w = pack2(x1.z, x1.w);
            WPA[t][j] = d;
        }
        {
            const float* s = W_h1h2 + j * HN + t * 8;
            float4 x0 = *(const float4*)s, x1 = *(const float4*)(s + 4);
            float4 d; d.x = pack2(x0.x, x0.y); d.y = pack2(x0.z, x0.w);
            d.z = pack2(x1.x, x1.y); d.w = pack2(x1.z, x1.w);
            WPB[t][j] = d;
        }
        {
            const float* s = W_h2h2 + j * HN + t * 8;
            float4 x0 = *(const float4*)s, x1 = *(const float4*)(s + 4);
            float4 d; d.x = pack2(x0.x, x0.y); d.y = pack2(x0.z, x0.w);
            d.z = pack2(x1.x, x1.y); d.w = pack2(x1.z, x1.w);
            WPC[t][j] = d;
        }
    }
    {
        const int t = tid >> 5, j = tid & 31;   // 512 = 16*32 exactly
        float4 d = {0.f, 0.f, 0.f, 0.f};
        if (j < ON) {
            const float* s = W_h2o + j * HN + t * 8;
            float4 x0 = *(const float4*)s, x1 = *(const float4*)(s + 4);
            d.x = pack2(x0.x, x0.y); d.y = pack2(x0.z, x0.w);
            d.z = pack2(x1.x, x1.y); d.w = pack2(x1.z, x1.w);
        }
        WPO[t][j] = d;
    }
    if (tid < HN) {
        s1h[0][tid] = (_Float16)0; s1h[1][tid] = (_Float16)0;
        s2h[0][tid] = (_Float16)0; s2h[1][tid] = (_Float16)0;
    }
    __syncthreads();

    if (w < 2) {
        // ================= S1: layer-1 LIF, j = w*64+lane =================
        const int j = (w << 6) + lane;
        float h1m = h1m0[b * HN + j];
        const float a1 = expf(-1.f / tau_m_h1[j]);
        const float r1 = expf(-1.f / tau_adp_h1[j]);
        const float bi = b_h1h1[j];
        float b1 = 0.01f, s1p = 0.f;
        const float* fp = ff + (size_t)b * TSTEPS * HN + j;
        float fc = fp[0], fn = fp[HN];
        for (int i = 0; i < TSTEPS + 4; ++i) {
            if (i < TSTEPS) {
                const float f2 = (i + 2 < TSTEPS) ? fp[(size_t)(i + 2) * HN] : 0.f;
                uint4 sv[16];
                LOADSPIKES(s1h, (i + 1) & 1, sv);          // s1(i-1)
                const float pA = mv1h(WPA, sv, j);
                b1 = r1 * b1 + (1.f - r1) * s1p;
                const float Bt = 0.01f + 1.8f * b1;
                h1m = h1m * a1 + (1.f - a1) * (fc + bi + pA) - Bt * s1p;
                s1p = (h1m - Bt > 0.f) ? 1.f : 0.f;
                s1h[i & 1][j] = (_Float16)s1p;
                fc = fn; fn = f2;
            }
            __syncthreads();
        }
    } else if (w < 4) {
        // ================= B: pB(i-1) = W_h1h2 . s1(i-1) =================
        const int j = ((w - 2) << 6) + lane;
        for (int i = 0; i < TSTEPS + 4; ++i) {
            if (i >= 1 && i <= TSTEPS) {
                uint4 sv[16];
                LOADSPIKES(s1h, (i - 1) & 1, sv);
                pBbuf[(i - 1) & 1][j] = mv1h(WPB, sv, j);
            }
            __syncthreads();
        }
    } else if (w < 6) {
        // ================= C + LIF2: s2(i-2), j = (w-4)*64+lane ============
        const int j = ((w - 4) << 6) + lane;
        float h2m = h2m0[b * HN + j];
        const float a2 = expf(-1.f / tau_m_h2[j]);
        const float r2 = expf(-1.f / tau_adp_h2[j]);
        const float bi = b_h1h2[j] + b_h2h2[j];
        float b2v = 0.01f, s2p = 0.f;
        for (int i = 0; i < TSTEPS + 4; ++i) {
            if (i >= 2 && i <= TSTEPS + 1) {
                const int k2 = i - 2;
                uint4 sv[16];
                LOADSPIKES(s2h, (k2 + 1) & 1, sv);         // s2(k2-1)
                const float pC = mv1h(WPC, sv, j);
                const float in2 = pBbuf[k2 & 1][j] + pC + bi;
                b2v = r2 * b2v + (1.f - r2) * s2p;
                const float Bt = 0.01f + 1.8f * b2v;
                h2m = h2m * a2 + (1.f - a2) * in2 - Bt * s2p;
                s2p = (h2m - Bt > 0.f) ? 1.f : 0.f;
                s2h[k2 & 1][j] = (_Float16)s2p;
            }
            __syncthreads();
        }
    } else if (w == 6) {
        // ================= RO: rdot(i-3) = W_h2o . s2(i-3) =================
        const int o = lane;
        for (int i = 0; i < TSTEPS + 4; ++i) {
            if (i >= 3 && i <= TSTEPS + 2 && o < ON) {
                const int k3 = i - 3;
                uint4 sv[16];
                LOADSPIKES(s2h, k3 & 1, sv);
                rdot_lds[k3 & 1][o] = mv1o(WPO, sv, o);
            }
            __syncthreads();
        }
    } else {
        // ================= OM: leaky readout + softmax accumulate ==========
        const int o = lane;
        float om = 0.f, ao = 0.f, bo = 0.f, acc = 0.f;
        if (o < ON) {
            om = om0[b * ON + o];
            ao = expf(-1.f / tau_m_o[o]);
            bo = b_h2o[o];
        }
        for (int i = 0; i < TSTEPS + 4; ++i) {
            if (i >= 4) {
                const int k4 = i - 4;
                if (o < ON)
                    om = om * ao + (1.f - ao) * (rdot_lds[k4 & 1][o] + bo);
                float mx = (o < ON) ? om : -3.4e38f;
#pragma unroll
                for (int m = 16; m >= 1; m >>= 1)
                    mx = fmaxf(mx, __shfl_xor(mx, m));
                float e = (o < ON) ? __expf(om - mx) : 0.f;
                float den = e;
#pragma unroll
                for (int m = 16; m >= 1; m >>= 1)
                    den += __shfl_xor(den, m);
                if (o < ON && k4 > 10) acc += e / den;
            }
            __syncthreads();
        }
        if (o < ON) out[b * ON + o] = acc;
    }
}

// ---------------------------------------------------------------------------
// Phase C: A_norm = sum|W_h1h1| + sum|W_h2h2|  -> out[5120]  (exact fp32)
// ---------------------------------------------------------------------------
__global__ void anorm_kernel(const float* __restrict__ W1,
                             const float* __restrict__ W2,
                             float* __restrict__ out) {
    __shared__ float red[256];
    float s = 0.f;
    for (int i = threadIdx.x; i < HN * HN; i += 256)
        s += fabsf(W1[i]) + fabsf(W2[i]);
    red[threadIdx.x] = s;
    __syncthreads();
    for (int off = 128; off > 0; off >>= 1) {
        if (threadIdx.x < off) red[threadIdx.x] += red[threadIdx.x + off];
        __syncthreads();
    }
    if (threadIdx.x == 0) out[256 * ON] = red[0];
}

extern "C" void kernel_launch(void* const* d_in, const int* in_sizes, int n_in,
                              void* d_out, int out_size, void* d_ws, size_t ws_size,
                              hipStream_t stream) {
    const float* input      = (const float*)d_in[0];
    // d_in[1], d_in[2]: A1_mask/A2_mask -- all-ones, unused by reference math
    const float* W_ih1      = (const float*)d_in[3];
    const float* b_ih1      = (const float*)d_in[4];
    const float* W_h1h1     = (const float*)d_in[5];
    const float* b_h1h1     = (const float*)d_in[6];
    const float* W_h1h2     = (const float*)d_in[7];
    const float* b_h1h2     = (const float*)d_in[8];
    const float* W_h2h2     = (const float*)d_in[9];
    const float* b_h2h2     = (const float*)d_in[10];
    const float* W_h2o      = (const float*)d_in[11];
    const float* b_h2o      = (const float*)d_in[12];
    const float* tau_adp_h1 = (const float*)d_in[13];
    const float* tau_adp_h2 = (const float*)d_in[14];
    const float* tau_m_h1   = (const float*)d_in[15];
    const float* tau_m_h2   = (const float*)d_in[16];
    const float* tau_m_o    = (const float*)d_in[17];
    const float* h1m0       = (const float*)d_in[18];
    const float* h2m0       = (const float*)d_in[19];
    const float* om0        = (const float*)d_in[20];

    float* out   = (float*)d_out;
    float* ffbuf = (float*)d_ws;   // 256*250*128*4 = 32.768 MB

    anorm_kernel<<<1, 256, 0, stream>>>(W_h1h1, W_h2h2, out);
    ff_gemm<<<500, 256, 0, stream>>>(input, W_ih1, b_ih1, ffbuf);
    srnn_pipe8<<<256, 512, 0, stream>>>(ffbuf, W_h1h1, b_h1h1, W_h1h2, b_h1h2,
                                        W_h2h2, b_h2h2, W_h2o, b_h2o,
                                        tau_adp_h1, tau_adp_h2,
                                        tau_m_h1, tau_m_h2, tau_m_o,
                                        h1m0, h2m0, om0, out);
}

// Round 13
// 221.758 us; speedup vs baseline: 1.5929x; 1.1817x over previous
//
#include <hip/hip_runtime.h>
#include <hip/hip_bf16.h>
#include <stdint.h>

#define HN 128      // hidden size
#define TSTEPS 250
#define ON 20       // output size
#define GK 700      // input size
#define NKT 22      // GEMM k-tiles of 32 (700 = 21*32 + 28, zero-padded)

typedef _Float16 h2 __attribute__((ext_vector_type(2)));
typedef _Float16 h8 __attribute__((ext_vector_type(8)));
typedef float f4 __attribute__((ext_vector_type(4)));

__device__ __forceinline__ uint32_t pack2u(float x, float y) {
    h2 p; p.x = (_Float16)x; p.y = (_Float16)y;
    return __builtin_bit_cast(uint32_t, p);
}

// ---------------------------------------------------------------------------
// Phase A: in1_ff[bt,h] = X[bt,:] . W_ih1[h,:] + b_ih1[h]
// M=64000, N=128, K=700(pad 704). f16 MFMA 16x16x32 (verified r12).
// ---------------------------------------------------------------------------
__global__ __launch_bounds__(256) void ff_gemm(const float* __restrict__ X,
                                               const float* __restrict__ W,
                                               const float* __restrict__ bias,
                                               float* __restrict__ out) {
    __shared__ __align__(16) uint32_t Xs[2][128][16];   // 8 KB x2 (f16 pairs)
    __shared__ __align__(16) uint32_t Ws[2][128][16];   // 8 KB x2
    const int tid   = threadIdx.x;
    const int w     = tid >> 6;
    const int lane  = tid & 63;
    const int m0    = blockIdx.x * 128;
    const int srow  = tid & 127;
    const int shalf = tid >> 7;
    const int lr    = lane & 15;
    const int lg    = lane >> 4;

    f4 acc[2][8];
#pragma unroll
    for (int m = 0; m < 2; ++m)
#pragma unroll
        for (int n = 0; n < 8; ++n) acc[m][n] = (f4){0.f, 0.f, 0.f, 0.f};

    float4 x4[4], w4[4];

#define LOADT(t)                                                               \
    {                                                                          \
        const int k0 = (t) * 32 + shalf * 16;                                  \
        if ((t) < 21 || shalf == 0) {                                          \
            _Pragma("unroll")                                                  \
            for (int q = 0; q < 4; ++q) {                                      \
                x4[q] = *(const float4*)&X[(size_t)(m0 + srow) * GK + k0 + q * 4]; \
                w4[q] = *(const float4*)&W[(size_t)srow * GK + k0 + q * 4];    \
            }                                                                  \
        } else {                                                               \
            _Pragma("unroll")                                                  \
            for (int q = 0; q < 3; ++q) {                                      \
                x4[q] = *(const float4*)&X[(size_t)(m0 + srow) * GK + k0 + q * 4]; \
                w4[q] = *(const float4*)&W[(size_t)srow * GK + k0 + q * 4];    \
            }                                                                  \
            x4[3] = (float4){0.f, 0.f, 0.f, 0.f};                              \
            w4[3] = (float4){0.f, 0.f, 0.f, 0.f};                              \
        }                                                                      \
    }
#define STORET(buf)                                                            \
    {                                                                          \
        _Pragma("unroll")                                                      \
        for (int q = 0; q < 4; ++q) {                                          \
            Xs[buf][srow][shalf * 8 + 2 * q]     = pack2u(x4[q].x, x4[q].y);   \
            Xs[buf][srow][shalf * 8 + 2 * q + 1] = pack2u(x4[q].z, x4[q].w);   \
            Ws[buf][srow][shalf * 8 + 2 * q]     = pack2u(w4[q].x, w4[q].y);   \
            Ws[buf][srow][shalf * 8 + 2 * q + 1] = pack2u(w4[q].z, w4[q].w);   \
        }                                                                      \
    }

    LOADT(0);
    STORET(0);
    __syncthreads();
    int cur = 0;
    for (int t = 0; t < NKT; ++t) {
        if (t + 1 < NKT) LOADT(t + 1);
        h8 a[2];
#pragma unroll
        for (int m = 0; m < 2; ++m) {
            const uint4 au = *(const uint4*)&Xs[cur][w * 32 + m * 16 + lr][lg * 4];
            a[m] = __builtin_bit_cast(h8, au);
        }
#pragma unroll
        for (int n = 0; n < 8; ++n) {
            const uint4 bu = *(const uint4*)&Ws[cur][n * 16 + lr][lg * 4];
            const h8 bf = __builtin_bit_cast(h8, bu);
            acc[0][n] = __builtin_amdgcn_mfma_f32_16x16x32_f16(a[0], bf, acc[0][n], 0, 0, 0);
            acc[1][n] = __builtin_amdgcn_mfma_f32_16x16x32_f16(a[1], bf, acc[1][n], 0, 0, 0);
        }
        if (t + 1 < NKT) STORET(cur ^ 1);
        __syncthreads();
        cur ^= 1;
    }

    float bv[8];
#pragma unroll
    for (int n = 0; n < 8; ++n) bv[n] = bias[n * 16 + lr];
#pragma unroll
    for (int m = 0; m < 2; ++m)
#pragma unroll
        for (int q = 0; q < 4; ++q) {
            const size_t row = (size_t)(m0 + w * 32 + m * 16 + lg * 4 + q);
#pragma unroll
            for (int n = 0; n < 8; ++n)
                out[row * HN + n * 16 + lr] = acc[m][n][q] + bv[n];
        }
#undef LOADT
#undef STORET
}

// ---------------------------------------------------------------------------
// i8 matvec helpers: weights WQ[g][j] = uint4 of 16 i8 (k = 16g..16g+15);
// spike vector sv[8] wave-uniform packed 0/1 bytes.
// 8 conflict-free ds_read_b128 + 32 v_dot4_i32_i8 per call.
// ---------------------------------------------------------------------------
__device__ __forceinline__ int mvq(const uint4 (&W)[8][HN],
                                   const uint4 (&sv)[8], int j) {
    int a = 0;
#pragma unroll
    for (int g = 0; g < 8; ++g) {
        const uint4 wq = W[g][j];
        const uint4 sq = sv[g];
        a = __builtin_amdgcn_sdot4((int)wq.x, (int)sq.x, a, false);
        a = __builtin_amdgcn_sdot4((int)wq.y, (int)sq.y, a, false);
        a = __builtin_amdgcn_sdot4((int)wq.z, (int)sq.z, a, false);
        a = __builtin_amdgcn_sdot4((int)wq.w, (int)sq.w, a, false);
    }
    return a;
}
__device__ __forceinline__ int mvqo(const uint4 (&W)[8][32],
                                    const uint4 (&sv)[8], int j) {
    int a = 0;
#pragma unroll
    for (int g = 0; g < 8; ++g) {
        const uint4 wq = W[g][j];
        const uint4 sq = sv[g];
        a = __builtin_amdgcn_sdot4((int)wq.x, (int)sq.x, a, false);
        a = __builtin_amdgcn_sdot4((int)wq.y, (int)sq.y, a, false);
        a = __builtin_amdgcn_sdot4((int)wq.z, (int)sq.z, a, false);
        a = __builtin_amdgcn_sdot4((int)wq.w, (int)sq.w, a, false);
    }
    return a;
}

#define LOADQ(arr, buf, sv)                                                    \
    {                                                                          \
        const uint4* _p = (const uint4*)&arr[buf][0];                          \
        _Pragma("unroll") for (int _g = 0; _g < 8; ++_g) sv[_g] = _p[_g];      \
    }

// ---------------------------------------------------------------------------
// Phase B: i8-LDS sdot4 pipeline, 6 heavy waves (all 8 waves working).
// One WG (512 thr) per batch row. Per-row i8 quantized weights in LDS
// (A+B+C 48 KB + O 4 KB); spikes as packed 0/1 bytes. Roles (slot i, one
// barrier each, verified offsets):
//   w0,w1: S1 -> s1(i)   w2,w3: B -> pB(i-1)   w4,w5: C+L2 -> s2(i-2)
//   w6: RO -> rdot(i-3)  w7: OM -> om/softmax(i-4)
// ---------------------------------------------------------------------------
__global__ __launch_bounds__(512) void srnn_pipe9(
    const float* __restrict__ ff,
    const float* __restrict__ W_h1h1, const float* __restrict__ b_h1h1,
    const float* __restrict__ W_h1h2, const float* __restrict__ b_h1h2,
    const float* __restrict__ W_h2h2, const float* __restrict__ b_h2h2,
    const float* __restrict__ W_h2o,  const float* __restrict__ b_h2o,
    const float* __restrict__ tau_adp_h1, const float* __restrict__ tau_adp_h2,
    const float* __restrict__ tau_m_h1,   const float* __restrict__ tau_m_h2,
    const float* __restrict__ tau_m_o,
    const float* __restrict__ h1m0, const float* __restrict__ h2m0,
    const float* __restrict__ om0,
    float* __restrict__ out) {
    const int b    = blockIdx.x;
    const int tid  = threadIdx.x;
    const int w    = tid >> 6;
    const int lane = tid & 63;

    __shared__ __align__(16) uint4 WQA[8][HN];   // 16 KB
    __shared__ __align__(16) uint4 WQB[8][HN];   // 16 KB
    __shared__ __align__(16) uint4 WQC[8][HN];   // 16 KB
    __shared__ __align__(16) uint4 WQO[8][32];   //  4 KB
    __shared__ float scA[HN], scB[HN], scC[HN], scO[32];
    __shared__ __align__(16) uint32_t s1w[2][32];
    __shared__ __align__(16) uint32_t s2w[2][32];
    __shared__ float pBbuf[2][HN];
    __shared__ float rdot_lds[2][32];

    // ---- stage: per-row i8 quantization (one time) ----
    if (tid < 416) {
        const int role = tid >> 7;          // 0:A 1:B 2:C 3:O-block
        const int j    = tid & 127;
        const bool isO = (role == 3);
        const bool on  = !isO || (j < 32);
        if (on) {
            const float* src = nullptr;
            bool valid = true;
            if (!isO) {
                src = (role == 0 ? W_h1h1 : role == 1 ? W_h1h2 : W_h2h2) + j * HN;
            } else if (j < ON) {
                src = W_h2o + j * HN;
            } else {
                valid = false;
            }
            float amax = 0.f;
            if (valid) {
#pragma unroll
                for (int q = 0; q < 32; ++q) {
                    float4 v = *(const float4*)&src[q * 4];
                    amax = fmaxf(amax, fmaxf(fmaxf(fabsf(v.x), fabsf(v.y)),
                                             fmaxf(fabsf(v.z), fabsf(v.w))));
                }
            }
            const float qs = (valid && amax > 0.f) ? 127.f / amax : 0.f;
#pragma unroll
            for (int g = 0; g < 8; ++g) {
                uint32_t u[4] = {0u, 0u, 0u, 0u};
                if (valid) {
#pragma unroll
                    for (int e = 0; e < 4; ++e) {
                        float4 v = *(const float4*)&src[g * 16 + e * 4];
                        const int q0 = (int)rintf(v.x * qs), q1 = (int)rintf(v.y * qs);
                        const int q2 = (int)rintf(v.z * qs), q3 = (int)rintf(v.w * qs);
                        u[e] = (uint32_t)(q0 & 255) | ((uint32_t)(q1 & 255) << 8) |
                               ((uint32_t)(q2 & 255) << 16) | ((uint32_t)(q3 & 255) << 24);
                    }
                }
                uint4 w4; w4.x = u[0]; w4.y = u[1]; w4.z = u[2]; w4.w = u[3];
                if (isO) WQO[g][j] = w4;
                else if (role == 0) WQA[g][j] = w4;
                else if (role == 1) WQB[g][j] = w4;
                else WQC[g][j] = w4;
            }
            const float os = (valid && amax > 0.f) ? amax / 127.f : 0.f;
            if (isO) scO[j] = os;
            else if (role == 0) scA[j] = os;
            else if (role == 1) scB[j] = os;
            else scC[j] = os;
        }
    }
    if (tid < 32) {
        s1w[0][tid] = 0u; s1w[1][tid] = 0u;
        s2w[0][tid] = 0u; s2w[1][tid] = 0u;
    }
    __syncthreads();

    if (w < 2) {
        // ================= S1: layer-1 LIF, j = w*64+lane =================
        const int j = (w << 6) + lane;
        const float sA = scA[j];
        float h1m = h1m0[b * HN + j];
        const float a1 = expf(-1.f / tau_m_h1[j]);
        const float r1 = expf(-1.f / tau_adp_h1[j]);
        const float bi = b_h1h1[j];
        float b1 = 0.01f, s1p = 0.f;
        const float* fp = ff + (size_t)b * TSTEPS * HN + j;
        float fc = fp[0], fn = fp[HN];
        for (int i = 0; i < TSTEPS + 4; ++i) {
            if (i < TSTEPS) {
                const float f2 = (i + 2 < TSTEPS) ? fp[(size_t)(i + 2) * HN] : 0.f;
                uint4 sv[8];
                LOADQ(s1w, (i + 1) & 1, sv);               // s1(i-1)
                const float pA = sA * (float)mvq(WQA, sv, j);
                b1 = r1 * b1 + (1.f - r1) * s1p;
                const float Bt = 0.01f + 1.8f * b1;
                h1m = h1m * a1 + (1.f - a1) * (fc + bi + pA) - Bt * s1p;
                const int sp = (h1m - Bt > 0.f) ? 1 : 0;
                s1p = (float)sp;
                int pk = sp | (__shfl_down(sp, 1) << 8) |
                         (__shfl_down(sp, 2) << 16) | (__shfl_down(sp, 3) << 24);
                if ((lane & 3) == 0) s1w[i & 1][(w << 4) + (lane >> 2)] = (uint32_t)pk;
                fc = fn; fn = f2;
            }
            __syncthreads();
        }
    } else if (w < 4) {
        // ================= B: pB(i-1) = W_h1h2 . s1(i-1) =================
        const int j = ((w - 2) << 6) + lane;
        const float sB = scB[j];
        for (int i = 0; i < TSTEPS + 4; ++i) {
            if (i >= 1 && i <= TSTEPS) {
                uint4 sv[8];
                LOADQ(s1w, (i - 1) & 1, sv);
                pBbuf[(i - 1) & 1][j] = sB * (float)mvq(WQB, sv, j);
            }
            __syncthreads();
        }
    } else if (w < 6) {
        // ================= C + LIF2: s2(i-2), j = (w-4)*64+lane ============
        const int j = ((w - 4) << 6) + lane;
        const float sC = scC[j];
        float h2m = h2m0[b * HN + j];
        const float a2 = expf(-1.f / tau_m_h2[j]);
        const float r2 = expf(-1.f / tau_adp_h2[j]);
        const float bi = b_h1h2[j] + b_h2h2[j];
        float b2v = 0.01f, s2p = 0.f;
        for (int i = 0; i < TSTEPS + 4; ++i) {
            if (i >= 2 && i <= TSTEPS + 1) {
                const int k2 = i - 2;
                uint4 sv[8];
                LOADQ(s2w, (k2 + 1) & 1, sv);              // s2(k2-1)
                const float pC = sC * (float)mvq(WQC, sv, j);
                const float in2 = pBbuf[k2 & 1][j] + pC + bi;
                b2v = r2 * b2v + (1.f - r2) * s2p;
                const float Bt = 0.01f + 1.8f * b2v;
                h2m = h2m * a2 + (1.f - a2) * in2 - Bt * s2p;
                const int sp = (h2m - Bt > 0.f) ? 1 : 0;
                s2p = (float)sp;
                int pk = sp | (__shfl_down(sp, 1) << 8) |
                         (__shfl_down(sp, 2) << 16) | (__shfl_down(sp, 3) << 24);
                if ((lane & 3) == 0) s2w[k2 & 1][((w - 4) << 4) + (lane >> 2)] = (uint32_t)pk;
            }
            __syncthreads();
        }
    } else if (w == 6) {
        // ================= RO: rdot(i-3) = W_h2o . s2(i-3) =================
        const int o = lane;
        const float sO = (o < 32) ? scO[o] : 0.f;
        for (int i = 0; i < TSTEPS + 4; ++i) {
            if (i >= 3 && i <= TSTEPS + 2 && o < ON) {
                const int k3 = i - 3;
                uint4 sv[8];
                LOADQ(s2w, k3 & 1, sv);
                rdot_lds[k3 & 1][o] = sO * (float)mvqo(WQO, sv, o);
            }
            __syncthreads();
        }
    } else {
        // ================= OM: leaky readout + softmax accumulate ==========
        const int o = lane;
        float om = 0.f, ao = 0.f, bo = 0.f, acc = 0.f;
        if (o < ON) {
            om = om0[b * ON + o];
            ao = expf(-1.f / tau_m_o[o]);
            bo = b_h2o[o];
        }
        for (int i = 0; i < TSTEPS + 4; ++i) {
            if (i >= 4) {
                const int k4 = i - 4;
                if (o < ON)
                    om = om * ao + (1.f - ao) * (rdot_lds[k4 & 1][o] + bo);
                float mx = (o < ON) ? om : -3.4e38f;
#pragma unroll
                for (int m = 16; m >= 1; m >>= 1)
                    mx = fmaxf(mx, __shfl_xor(mx, m));
                float e = (o < ON) ? __expf(om - mx) : 0.f;
                float den = e;
#pragma unroll
                for (int m = 16; m >= 1; m >>= 1)
                    den += __shfl_xor(den, m);
                if (o < ON && k4 > 10) acc += e / den;
            }
            __syncthreads();
        }
        if (o < ON) out[b * ON + o] = acc;
    }
}

// ---------------------------------------------------------------------------
// Phase C: A_norm = sum|W_h1h1| + sum|W_h2h2|  -> out[5120]  (exact fp32)
// ---------------------------------------------------------------------------
__global__ void anorm_kernel(const float* __restrict__ W1,
                             const float* __restrict__ W2,
                             float* __restrict__ out) {
    __shared__ float red[256];
    float s = 0.f;
    for (int i = threadIdx.x; i < HN * HN; i += 256)
        s += fabsf(W1[i]) + fabsf(W2[i]);
    red[threadIdx.x] = s;
    __syncthreads();
    for (int off = 128; off > 0; off >>= 1) {
        if (threadIdx.x < off) red[threadIdx.x] += red[threadIdx.x + off];
        __syncthreads();
    }
    if (threadIdx.x == 0) out[256 * ON] = red[0];
}

extern "C" void kernel_launch(void* const* d_in, const int* in_sizes, int n_in,
                              void* d_out, int out_size, void* d_ws, size_t ws_size,
                              hipStream_t stream) {
    const float* input      = (const float*)d_in[0];
    // d_in[1], d_in[2]: A1_mask/A2_mask -- all-ones, unused by reference math
    const float* W_ih1      = (const float*)d_in[3];
    const float* b_ih1      = (const float*)d_in[4];
    const float* W_h1h1     = (const float*)d_in[5];
    const float* b_h1h1     = (const float*)d_in[6];
    const float* W_h1h2     = (const float*)d_in[7];
    const float* b_h1h2     = (const float*)d_in[8];
    const float* W_h2h2     = (const float*)d_in[9];
    const float* b_h2h2     = (const float*)d_in[10];
    const float* W_h2o      = (const float*)d_in[11];
    const float* b_h2o      = (const float*)d_in[12];
    const float* tau_adp_h1 = (const float*)d_in[13];
    const float* tau_adp_h2 = (const float*)d_in[14];
    const float* tau_m_h1   = (const float*)d_in[15];
    const float* tau_m_h2   = (const float*)d_in[16];
    const float* tau_m_o    = (const float*)d_in[17];
    const float* h1m0       = (const float*)d_in[18];
    const float* h2m0       = (const float*)d_in[19];
    const float* om0        = (const float*)d_in[20];

    float* out   = (float*)d_out;
    float* ffbuf = (float*)d_ws;   // 256*250*128*4 = 32.768 MB

    anorm_kernel<<<1, 256, 0, stream>>>(W_h1h1, W_h2h2, out);
    ff_gemm<<<500, 256, 0, stream>>>(input, W_ih1, b_ih1, ffbuf);
    srnn_pipe9<<<256, 512, 0, stream>>>(ffbuf, W_h1h1, b_h1h1, W_h1h2, b_h1h2,
                                        W_h2h2, b_h2h2, W_h2o, b_h2o,
                                        tau_adp_h1, tau_adp_h2,
                                        tau_m_h1, tau_m_h2, tau_m_o,
                                        h1m0, h2m0, om0, out);
}